// Round 1
// baseline (1040.099 us; speedup 1.0000x reference)
//
#include <hip/hip_runtime.h>

#define NRAYS 4096
#define PSAMP 254      // 231 inner + 23 outer samples
#define NIN   231
#define GR    160
#define GR2   25600
#define GR3   4096000
#define MLPW  128
#define D0    39
#define K0C   12

__device__ __forceinline__ float sigmoidf_(float x) { return 1.0f / (1.0f + __expf(-x)); }

__global__ __launch_bounds__(256, 2) void voxgo_fused(
    const float* __restrict__ rays_o, const float* __restrict__ rays_d,
    const float* __restrict__ viewdirs, const float* __restrict__ dg,
    const float* __restrict__ k0g, const float* __restrict__ w0,
    const float* __restrict__ b0, const float* __restrict__ w1,
    const float* __restrict__ b1, const float* __restrict__ w2,
    const float* __restrict__ b2, float* __restrict__ out)
{
    const int r   = blockIdx.x;
    const int tid = threadIdx.x;

    __shared__ float feat_s[D0 * 256];   // [k][tid]: stride-1 across lanes (2-way aliasing = free)
    __shared__ float sc[256];            // transmittance scan
    __shared__ float red[3][256];        // final reduction

    // ---- per-ray data (uniform across block; broadcast loads) ----
    const float ox = rays_o[3*r+0], oy = rays_o[3*r+1], oz = rays_o[3*r+2];
    float dxv = rays_d[3*r+0], dyv = rays_d[3*r+1], dzv = rays_d[3*r+2];
    const float vdx = viewdirs[3*r+0], vdy = viewdirs[3*r+1], vdz = viewdirs[3*r+2];
    const float rinv = rsqrtf(dxv*dxv + dyv*dyv + dzv*dzv);
    dxv *= rinv; dyv *= rinv; dzv *= rinv;

    // ---- sample distance t ----
    float t;
    if (tid < NIN) {
        t = ((float)tid + 0.5f) * (2.0f * 1.7320508075688772f / 231.0f);
    } else {
        const float lstep = 0.999f / 23.0f;
        const int j = tid - NIN;                      // tids 254,255: finite junk; weight=0 kills it
        const float L0 = 1.0f - (float)j * lstep;
        const float L1 = 1.0f - (float)(j+1) * lstep;
        t = 1.7320508075688772f * (1.0f/L0 + 1.0f/L1);
    }

    // ---- point + contraction ----
    float px = fmaf(dxv, t, ox), py = fmaf(dyv, t, oy), pz = fmaf(dzv, t, oz);
    const float nrm = fmaxf(fabsf(px), fmaxf(fabsf(py), fabsf(pz)));
    if (nrm > 1.0f) {
        const float s = (1.2f - 0.2f / nrm) / nrm;
        px *= s; py *= s; pz *= s;
    }

    // ---- grid coords (align_corners=True) ----
    const float gsc = 159.0f / 2.4f;
    const float gx = fminf(fmaxf((px + 1.2f) * gsc, 0.0f), 159.0f);
    const float gy = fminf(fmaxf((py + 1.2f) * gsc, 0.0f), 159.0f);
    const float gz = fminf(fmaxf((pz + 1.2f) * gsc, 0.0f), 159.0f);
    const int x0 = min((int)gx, GR-2), y0 = min((int)gy, GR-2), z0 = min((int)gz, GR-2);
    const float fx = gx - (float)x0, fy = gy - (float)y0, fz = gz - (float)z0;
    const int base = x0*GR2 + y0*GR + z0;

    // ---- density trilinear -> alpha ----
    const float d000 = dg[base],        d001 = dg[base+1];
    const float d010 = dg[base+GR],     d011 = dg[base+GR+1];
    const float d100 = dg[base+GR2],    d101 = dg[base+GR2+1];
    const float d110 = dg[base+GR2+GR], d111 = dg[base+GR2+GR+1];
    const float c00 = d000*(1.0f-fz) + d001*fz;
    const float c01 = d010*(1.0f-fz) + d011*fz;
    const float c10 = d100*(1.0f-fz) + d101*fz;
    const float c11 = d110*(1.0f-fz) + d111*fz;
    const float dens = (c00*(1.0f-fy) + c01*fy)*(1.0f-fx) + (c10*(1.0f-fy) + c11*fy)*fx;

    const float ACT_SHIFT = -9.21024036697535f;       // log(1/(1-1e-4)-1)
    const float alpha = (tid < PSAMP) ? sigmoidf_(dens + ACT_SHIFT) : 0.0f;

    // ---- inclusive product scan of (1-alpha) ----
    sc[tid] = 1.0f - alpha;
    __syncthreads();
    #pragma unroll
    for (int off = 1; off < 256; off <<= 1) {
        const float v = (tid >= off) ? sc[tid - off] : 1.0f;
        __syncthreads();
        sc[tid] *= v;
        __syncthreads();
    }
    const float T_excl    = (tid == 0) ? 1.0f : sc[tid-1];
    const float weight    = alpha * T_excl;
    const float ainv_last = sc[PSAMP-1];

    // ---- k0 trilinear (12 ch) + view embedding -> feat in LDS ----
    const float wx0 = 1.0f-fx, wy0 = 1.0f-fy, wz0 = 1.0f-fz;
    const float w000 = wx0*wy0*wz0, w001 = wx0*wy0*fz, w010 = wx0*fy*wz0, w011 = wx0*fy*fz;
    const float w100 = fx*wy0*wz0,  w101 = fx*wy0*fz,  w110 = fx*fy*wz0,  w111 = fx*fy*fz;
    #pragma unroll
    for (int c = 0; c < K0C; c++) {
        const float* g = k0g + c*GR3 + base;
        const float v = w000*g[0]      + w001*g[1]
                      + w010*g[GR]     + w011*g[GR+1]
                      + w100*g[GR2]    + w101*g[GR2+1]
                      + w110*g[GR2+GR] + w111*g[GR2+GR+1];
        feat_s[c*256 + tid] = v;
    }
    feat_s[12*256 + tid] = vdx;
    feat_s[13*256 + tid] = vdy;
    feat_s[14*256 + tid] = vdz;
    #pragma unroll
    for (int p = 0; p < 4; p++) {
        const float f = (float)(1 << p);
        feat_s[(15+p)*256 + tid] = __sinf(vdx*f);
        feat_s[(19+p)*256 + tid] = __sinf(vdy*f);
        feat_s[(23+p)*256 + tid] = __sinf(vdz*f);
        feat_s[(27+p)*256 + tid] = __cosf(vdx*f);
        feat_s[(31+p)*256 + tid] = __cosf(vdy*f);
        feat_s[(35+p)*256 + tid] = __cosf(vdz*f);
    }
    // each thread reads only its own feat column -> no sync needed

    // ---- layer 1: h1 = relu(feat @ w0 + b0) ----
    float h1[MLPW];
    {
        const float4* b0v = (const float4*)b0;
        #pragma unroll
        for (int j4 = 0; j4 < MLPW/4; j4++) {
            const float4 b = b0v[j4];
            h1[4*j4+0] = b.x; h1[4*j4+1] = b.y; h1[4*j4+2] = b.z; h1[4*j4+3] = b.w;
        }
    }
    for (int k = 0; k < D0; k++) {
        const float fk = feat_s[k*256 + tid];
        const float4* row = (const float4*)(w0 + k*MLPW);   // wave-uniform address
        #pragma unroll
        for (int j4 = 0; j4 < MLPW/4; j4++) {
            const float4 wv = row[j4];
            h1[4*j4+0] = fmaf(fk, wv.x, h1[4*j4+0]);
            h1[4*j4+1] = fmaf(fk, wv.y, h1[4*j4+1]);
            h1[4*j4+2] = fmaf(fk, wv.z, h1[4*j4+2]);
            h1[4*j4+3] = fmaf(fk, wv.w, h1[4*j4+3]);
        }
    }
    #pragma unroll
    for (int j = 0; j < MLPW; j++) h1[j] = fmaxf(h1[j], 0.0f);

    // ---- layers 2+3 fused ----
    float ar = b2[0], ag = b2[1], ab_ = b2[2];
    for (int j4 = 0; j4 < MLPW/4; j4++) {
        float4 a = ((const float4*)b1)[j4];
        #pragma unroll
        for (int k = 0; k < MLPW; k++) {
            const float4 wv = ((const float4*)(w1 + k*MLPW))[j4];
            a.x = fmaf(h1[k], wv.x, a.x);
            a.y = fmaf(h1[k], wv.y, a.y);
            a.z = fmaf(h1[k], wv.z, a.z);
            a.w = fmaf(h1[k], wv.w, a.w);
        }
        const int j = 4*j4;
        const float h2x = fmaxf(a.x, 0.0f), h2y = fmaxf(a.y, 0.0f);
        const float h2z = fmaxf(a.z, 0.0f), h2w = fmaxf(a.w, 0.0f);
        ar = fmaf(h2x, w2[(j+0)*3+0], ar); ag = fmaf(h2x, w2[(j+0)*3+1], ag); ab_ = fmaf(h2x, w2[(j+0)*3+2], ab_);
        ar = fmaf(h2y, w2[(j+1)*3+0], ar); ag = fmaf(h2y, w2[(j+1)*3+1], ag); ab_ = fmaf(h2y, w2[(j+1)*3+2], ab_);
        ar = fmaf(h2z, w2[(j+2)*3+0], ar); ag = fmaf(h2z, w2[(j+2)*3+1], ag); ab_ = fmaf(h2z, w2[(j+2)*3+2], ab_);
        ar = fmaf(h2w, w2[(j+3)*3+0], ar); ag = fmaf(h2w, w2[(j+3)*3+1], ag); ab_ = fmaf(h2w, w2[(j+3)*3+2], ab_);
    }
    const float rr = sigmoidf_(ar), rg = sigmoidf_(ag), rb = sigmoidf_(ab_);

    // ---- weighted reduction over samples ----
    red[0][tid] = weight * rr;
    red[1][tid] = weight * rg;
    red[2][tid] = weight * rb;
    __syncthreads();
    #pragma unroll
    for (int s = 128; s > 0; s >>= 1) {
        if (tid < s) {
            red[0][tid] += red[0][tid+s];
            red[1][tid] += red[1][tid+s];
            red[2][tid] += red[2][tid+s];
        }
        __syncthreads();
    }
    if (tid == 0) {
        out[3*r+0] = red[0][0] + ainv_last;   // BG = 1.0
        out[3*r+1] = red[1][0] + ainv_last;
        out[3*r+2] = red[2][0] + ainv_last;
    }
}

extern "C" void kernel_launch(void* const* d_in, const int* in_sizes, int n_in,
                              void* d_out, int out_size, void* d_ws, size_t ws_size,
                              hipStream_t stream) {
    (void)in_sizes; (void)n_in; (void)out_size; (void)d_ws; (void)ws_size;
    voxgo_fused<<<NRAYS, 256, 0, stream>>>(
        (const float*)d_in[0],  // rays_o
        (const float*)d_in[1],  // rays_d
        (const float*)d_in[2],  // viewdirs
        (const float*)d_in[3],  // density_grid
        (const float*)d_in[4],  // k0_grid
        (const float*)d_in[5],  // w0
        (const float*)d_in[6],  // b0
        (const float*)d_in[7],  // w1
        (const float*)d_in[8],  // b1
        (const float*)d_in[9],  // w2
        (const float*)d_in[10], // b2
        (float*)d_out);         // d_in[11] = stepsize (always 1; baked into constants)
}

// Round 2
// 525.955 us; speedup vs baseline: 1.9775x; 1.9775x over previous
//
#include <hip/hip_runtime.h>

#define NRAYS 4096
#define PSAMP 254      // 231 inner + 23 outer samples
#define NIN   231
#define GR    160
#define GR2   25600
#define GR3   4096000
#define SROW  136      // h-buffer row stride in bf16 elems (272 B, 16B-aligned, 4-bank rotation)

typedef __attribute__((ext_vector_type(8))) short bf16x8;
typedef __attribute__((ext_vector_type(4))) float f32x4;

__device__ __forceinline__ unsigned short f2bf(float x) {
    union { float f; unsigned u; } v; v.f = x;
    return (unsigned short)((v.u + 0x7fffu + ((v.u >> 16) & 1u)) >> 16);
}
__device__ __forceinline__ float sigmoidf_(float x) { return 1.0f / (1.0f + __expf(-x)); }

// Pack W[K x N] (row-major fp32, row stride ldw) into MFMA B-fragment order, bf16.
// frag f = nt*KS + ks; lane l: n = nt*16 + (l&15), k = ks*32 + (l>>4)*8 + j (j=0..7).
// out[(f*64 + l)*8 + j]. Zero-pads k>=K and n>=N.
__global__ void prepack(const float* __restrict__ w, unsigned short* __restrict__ out,
                        int K, int N, int ldw, int NT, int KS) {
    const int idx = blockIdx.x * 256 + threadIdx.x;
    if (idx >= NT * KS * 64) return;
    const int l  = idx & 63, f = idx >> 6;
    const int ks = f % KS,  nt = f / KS;
    const int n  = nt * 16 + (l & 15);
    const int k0 = ks * 32 + (l >> 4) * 8;
    unsigned p[4];
    #pragma unroll
    for (int q = 0; q < 4; q++) {
        const int ka = k0 + 2 * q, kb = ka + 1;
        const float va = (ka < K && n < N) ? w[ka * ldw + n] : 0.0f;
        const float vb = (kb < K && n < N) ? w[kb * ldw + n] : 0.0f;
        p[q] = (unsigned)f2bf(va) | ((unsigned)f2bf(vb) << 16);
    }
    uint4 v; v.x = p[0]; v.y = p[1]; v.z = p[2]; v.w = p[3];
    ((uint4*)out)[idx] = v;
}

__global__ __launch_bounds__(256, 2) void voxgo_mfma(
    const float* __restrict__ rays_o, const float* __restrict__ rays_d,
    const float* __restrict__ viewdirs, const float* __restrict__ dg,
    const float* __restrict__ k0g,
    const float* __restrict__ b0, const float* __restrict__ b1,
    const float* __restrict__ b2,
    const unsigned short* __restrict__ pw0, const unsigned short* __restrict__ pw1,
    const unsigned short* __restrict__ pw2,
    float* __restrict__ out)
{
    const int r    = blockIdx.x;
    const int tid  = threadIdx.x;
    const int wv   = tid >> 6, lane = tid & 63, quad = lane >> 4, l16 = lane & 15;

    __shared__ unsigned short hbuf[4][64 * SROW];  // per-wave: feat, then h1, then h2
    __shared__ float sc[256];                      // transmittance scan
    __shared__ float wgt[256];                     // per-sample weights
    __shared__ float redbuf[256];                  // final reduction

    // ================= phase 1: per-sample geometry + density =================
    const float ox = rays_o[3*r+0], oy = rays_o[3*r+1], oz = rays_o[3*r+2];
    float dxv = rays_d[3*r+0], dyv = rays_d[3*r+1], dzv = rays_d[3*r+2];
    const float vdx = viewdirs[3*r+0], vdy = viewdirs[3*r+1], vdz = viewdirs[3*r+2];
    const float rinv = rsqrtf(dxv*dxv + dyv*dyv + dzv*dzv);
    dxv *= rinv; dyv *= rinv; dzv *= rinv;

    float t;
    if (tid < NIN) {
        t = ((float)tid + 0.5f) * (2.0f * 1.7320508075688772f / 231.0f);
    } else {
        const float lstep = 0.999f / 23.0f;
        const int j = tid - NIN;                   // tids 254,255: finite junk; weight=0 kills it
        const float L0 = 1.0f - (float)j * lstep;
        const float L1 = 1.0f - (float)(j+1) * lstep;
        t = 1.7320508075688772f * (1.0f/L0 + 1.0f/L1);
    }

    float px = fmaf(dxv, t, ox), py = fmaf(dyv, t, oy), pz = fmaf(dzv, t, oz);
    const float nrm = fmaxf(fabsf(px), fmaxf(fabsf(py), fabsf(pz)));
    if (nrm > 1.0f) {
        const float s = (1.2f - 0.2f / nrm) / nrm;
        px *= s; py *= s; pz *= s;
    }

    const float gsc = 159.0f / 2.4f;
    const float gx = fminf(fmaxf((px + 1.2f) * gsc, 0.0f), 159.0f);
    const float gy = fminf(fmaxf((py + 1.2f) * gsc, 0.0f), 159.0f);
    const float gz = fminf(fmaxf((pz + 1.2f) * gsc, 0.0f), 159.0f);
    const int x0 = min((int)gx, GR-2), y0 = min((int)gy, GR-2), z0 = min((int)gz, GR-2);
    const float fx = gx - (float)x0, fy = gy - (float)y0, fz = gz - (float)z0;
    const int base = x0*GR2 + y0*GR + z0;

    const float d000 = dg[base],        d001 = dg[base+1];
    const float d010 = dg[base+GR],     d011 = dg[base+GR+1];
    const float d100 = dg[base+GR2],    d101 = dg[base+GR2+1];
    const float d110 = dg[base+GR2+GR], d111 = dg[base+GR2+GR+1];
    const float c00 = d000*(1.0f-fz) + d001*fz;
    const float c01 = d010*(1.0f-fz) + d011*fz;
    const float c10 = d100*(1.0f-fz) + d101*fz;
    const float c11 = d110*(1.0f-fz) + d111*fz;
    const float dens = (c00*(1.0f-fy) + c01*fy)*(1.0f-fx) + (c10*(1.0f-fy) + c11*fy)*fx;

    const float ACT_SHIFT = -9.21024036697535f;    // log(1/(1-1e-4)-1)
    const float alpha = (tid < PSAMP) ? sigmoidf_(dens + ACT_SHIFT) : 0.0f;

    // ---- inclusive product scan of (1-alpha), fp32 ----
    sc[tid] = 1.0f - alpha;
    __syncthreads();
    #pragma unroll
    for (int off = 1; off < 256; off <<= 1) {
        const float v = (tid >= off) ? sc[tid - off] : 1.0f;
        __syncthreads();
        sc[tid] *= v;
        __syncthreads();
    }
    const float T_excl = (tid == 0) ? 1.0f : sc[tid-1];
    wgt[tid] = alpha * T_excl;

    // ================= phase 2: feat -> LDS bf16 (MFMA A-readable) =================
    const float wx0 = 1.0f-fx, wy0 = 1.0f-fy, wz0 = 1.0f-fz;
    const float w000 = wx0*wy0*wz0, w001 = wx0*wy0*fz, w010 = wx0*fy*wz0, w011 = wx0*fy*fz;
    const float w100 = fx*wy0*wz0,  w101 = fx*wy0*fz,  w110 = fx*fy*wz0,  w111 = fx*fy*fz;

    float fv[40];
    #pragma unroll
    for (int c = 0; c < 12; c++) {
        const float* g = k0g + c*GR3 + base;
        fv[c] = w000*g[0]      + w001*g[1]
              + w010*g[GR]     + w011*g[GR+1]
              + w100*g[GR2]    + w101*g[GR2+1]
              + w110*g[GR2+GR] + w111*g[GR2+GR+1];
    }
    fv[12] = vdx; fv[13] = vdy; fv[14] = vdz;
    #pragma unroll
    for (int p = 0; p < 4; p++) {
        const float f = (float)(1 << p);
        fv[15+p] = __sinf(vdx*f);  fv[19+p] = __sinf(vdy*f);  fv[23+p] = __sinf(vdz*f);
        fv[27+p] = __cosf(vdx*f);  fv[31+p] = __cosf(vdy*f);  fv[35+p] = __cosf(vdz*f);
    }
    fv[39] = 0.0f;

    unsigned short* hb = &hbuf[wv][0];
    {
        const int row = tid & 63;
        uint4* dst = (uint4*)(hb + row * SROW);
        #pragma unroll
        for (int i = 0; i < 8; i++) {
            unsigned p[4];
            #pragma unroll
            for (int q = 0; q < 4; q++) {
                const int e0 = i*8 + 2*q, e1 = e0 + 1;
                const unsigned lo = (e0 < 39) ? f2bf(fv[e0]) : 0u;
                const unsigned hi = (e1 < 39) ? f2bf(fv[e1]) : 0u;
                p[q] = lo | (hi << 16);
            }
            uint4 v; v.x = p[0]; v.y = p[1]; v.z = p[2]; v.w = p[3];
            dst[i] = v;
        }
    }
    __syncthreads();

    // ================= phase 3: MLP via MFMA (per-wave, 64 samples each) =========
    // A-frag for (mt,ks): lane reads 16B at row (mt*16+l16), k = ks*32+quad*8
    // C-frag element e: row = quad*4+e, col = nt*16+l16   [verified layouts, §3]

    // ---- layer 1: h1 = relu(feat @ w0 + b0)  (K=64 padded, N=128) ----
    f32x4 acc1[4][8];
    #pragma unroll
    for (int nt = 0; nt < 8; nt++) {
        const float bz = b0[nt*16 + l16];
        #pragma unroll
        for (int mt = 0; mt < 4; mt++) { f32x4 z = {bz,bz,bz,bz}; acc1[mt][nt] = z; }
    }
    #pragma unroll
    for (int ks = 0; ks < 2; ks++) {
        bf16x8 a[4];
        #pragma unroll
        for (int mt = 0; mt < 4; mt++)
            a[mt] = *(const bf16x8*)(hb + (mt*16 + l16)*SROW + ks*32 + quad*8);
        #pragma unroll
        for (int nt = 0; nt < 8; nt++) {
            const bf16x8 b = *(const bf16x8*)(pw0 + ((nt*2 + ks)*64 + lane)*8);
            #pragma unroll
            for (int mt = 0; mt < 4; mt++)
                acc1[mt][nt] = __builtin_amdgcn_mfma_f32_16x16x32_bf16(a[mt], b, acc1[mt][nt], 0,0,0);
        }
    }
    #pragma unroll
    for (int mt = 0; mt < 4; mt++)
        #pragma unroll
        for (int nt = 0; nt < 8; nt++)
            #pragma unroll
            for (int e = 0; e < 4; e++)
                hb[(mt*16 + quad*4 + e)*SROW + nt*16 + l16] = f2bf(fmaxf(acc1[mt][nt][e], 0.0f));
    __syncthreads();

    // ---- layer 2: h2 = relu(h1 @ w1 + b1)  (K=128, N=128) ----
    f32x4 acc2[4][8];
    #pragma unroll
    for (int nt = 0; nt < 8; nt++) {
        const float bz = b1[nt*16 + l16];
        #pragma unroll
        for (int mt = 0; mt < 4; mt++) { f32x4 z = {bz,bz,bz,bz}; acc2[mt][nt] = z; }
    }
    #pragma unroll
    for (int ks = 0; ks < 4; ks++) {
        bf16x8 a[4];
        #pragma unroll
        for (int mt = 0; mt < 4; mt++)
            a[mt] = *(const bf16x8*)(hb + (mt*16 + l16)*SROW + ks*32 + quad*8);
        #pragma unroll
        for (int nt = 0; nt < 8; nt++) {
            const bf16x8 b = *(const bf16x8*)(pw1 + ((nt*4 + ks)*64 + lane)*8);
            #pragma unroll
            for (int mt = 0; mt < 4; mt++)
                acc2[mt][nt] = __builtin_amdgcn_mfma_f32_16x16x32_bf16(a[mt], b, acc2[mt][nt], 0,0,0);
        }
    }
    #pragma unroll
    for (int mt = 0; mt < 4; mt++)
        #pragma unroll
        for (int nt = 0; nt < 8; nt++)
            #pragma unroll
            for (int e = 0; e < 4; e++)
                hb[(mt*16 + quad*4 + e)*SROW + nt*16 + l16] = f2bf(fmaxf(acc2[mt][nt][e], 0.0f));
    __syncthreads();

    // ---- layer 3: rgb_logit = h2 @ w2 + b2  (K=128, N=16 padded from 3) ----
    f32x4 acc3[4];
    {
        const float bz = (l16 < 3) ? b2[l16] : 0.0f;
        #pragma unroll
        for (int mt = 0; mt < 4; mt++) { f32x4 z = {bz,bz,bz,bz}; acc3[mt] = z; }
    }
    #pragma unroll
    for (int ks = 0; ks < 4; ks++) {
        const bf16x8 b = *(const bf16x8*)(pw2 + (ks*64 + lane)*8);
        #pragma unroll
        for (int mt = 0; mt < 4; mt++) {
            const bf16x8 a = *(const bf16x8*)(hb + (mt*16 + l16)*SROW + ks*32 + quad*8);
            acc3[mt] = __builtin_amdgcn_mfma_f32_16x16x32_bf16(a, b, acc3[mt], 0,0,0);
        }
    }

    // ================= epilogue: sigmoid + weighted reduce =================
    float contrib = 0.0f;
    #pragma unroll
    for (int mt = 0; mt < 4; mt++)
        #pragma unroll
        for (int e = 0; e < 4; e++) {
            const float s = sigmoidf_(acc3[mt][e]);
            contrib += wgt[wv*64 + mt*16 + quad*4 + e] * s;
        }
    redbuf[tid] = contrib;
    __syncthreads();
    if (tid < 3) {
        float acc_o = sc[PSAMP-1];                 // alphainv_last * BG(=1)
        #pragma unroll
        for (int w = 0; w < 4; w++)
            #pragma unroll
            for (int q = 0; q < 4; q++)
                acc_o += redbuf[w*64 + q*16 + tid];
        out[3*r + tid] = acc_o;
    }
}

extern "C" void kernel_launch(void* const* d_in, const int* in_sizes, int n_in,
                              void* d_out, int out_size, void* d_ws, size_t ws_size,
                              hipStream_t stream) {
    (void)in_sizes; (void)n_in; (void)out_size; (void)ws_size;
    unsigned short* pw0 = (unsigned short*)d_ws;           // 16 frags * 1KB = 16 KB
    unsigned short* pw1 = pw0 + 16*64*8;                   // 32 frags = 32 KB
    unsigned short* pw2 = pw1 + 32*64*8;                   // 4 frags  =  4 KB

    prepack<<<4, 256, 0, stream>>>((const float*)d_in[5], pw0,  39, 128, 128, 8, 2);
    prepack<<<8, 256, 0, stream>>>((const float*)d_in[7], pw1, 128, 128, 128, 8, 4);
    prepack<<<1, 256, 0, stream>>>((const float*)d_in[9], pw2, 128,   3,   3, 1, 4);

    voxgo_mfma<<<NRAYS, 256, 0, stream>>>(
        (const float*)d_in[0],  // rays_o
        (const float*)d_in[1],  // rays_d
        (const float*)d_in[2],  // viewdirs
        (const float*)d_in[3],  // density_grid
        (const float*)d_in[4],  // k0_grid
        (const float*)d_in[6],  // b0
        (const float*)d_in[8],  // b1
        (const float*)d_in[10], // b2
        pw0, pw1, pw2,
        (float*)d_out);         // d_in[11] = stepsize (always 1; baked in)
}